// Round 3
// baseline (351.278 us; speedup 1.0000x reference)
//
#include <hip/hip_runtime.h>
#include <hip/hip_bf16.h>

#define NC 10
#define DD 64
#define BB 32
#define SS 16384
#define SCHUNKS 32
#define ROWS_PER_BLOCK (SS / SCHUNKS)        // 512
#define ROWS_PER_WAVE  (ROWS_PER_BLOCK / 4)  // 128

// ws layout (primary path): seg [BB*NC*DD] f32 | cnt [BB*NC] i32  = 83,200 B
#define WS_WORDS (BB * NC * DD + BB * NC)    // 20800 words

// ---------------------------------------------------------------- zero ws ---
__global__ __launch_bounds__(256) void zero_ws_kernel(int* __restrict__ w, int n) {
    int i = blockIdx.x * 256 + threadIdx.x;
    if (i < n) w[i] = 0;
}

// ------------------------------------------------- kernel 1: segment sums ---
// 1024 blocks (32 b x 32 chunks) x 256 thr. One wave per row (lane = dim):
// ds_add_f32 into LDS[10][64]; banks = lane%32 -> 2 lanes/bank = free (m136).
// Block partials combine via global f32 atomics (32 writers per address).
__global__ __launch_bounds__(256) void seg_kernel(
    const float* __restrict__ x, const int* __restrict__ labels,
    float* __restrict__ seg, int* __restrict__ cnt)
{
    __shared__ float ssum[NC * DD];
    __shared__ int scnt[NC];
    const int tid = threadIdx.x;
    const int blk = blockIdx.x;
    const int b = blk / SCHUNKS, chunk = blk % SCHUNKS;
    const int s0 = chunk * ROWS_PER_BLOCK;

    for (int i = tid; i < NC * DD; i += 256) ssum[i] = 0.f;
    if (tid < NC) scnt[tid] = 0;
    __syncthreads();

    const int* lab = labels + b * SS + s0;
    atomicAdd(&scnt[lab[tid]], 1);
    atomicAdd(&scnt[lab[tid + 256]], 1);

    const int wave = tid >> 6, lane = tid & 63;
    const float* xb = x + ((long)b * SS + s0 + wave * ROWS_PER_WAVE) * DD + lane;
    const int* labw = lab + wave * ROWS_PER_WAVE;

    for (int r = 0; r < ROWS_PER_WAVE; r += 8) {
        float v[8]; int l[8];
        #pragma unroll
        for (int u = 0; u < 8; ++u) {             // 8 rows in flight
            v[u] = xb[(r + u) * DD];              // 256B coalesced per row
            l[u] = labw[r + u];                   // broadcast (L1)
        }
        #pragma unroll
        for (int u = 0; u < 8; ++u)
            atomicAdd(&ssum[l[u] * DD + lane], v[u]);  // ds_add_f32, no branch
    }
    __syncthreads();

    float* segb = seg + (long)b * (NC * DD);
    for (int i = tid; i < NC * DD; i += 256) atomicAdd(&segb[i], ssum[i]);
    if (tid < NC) atomicAdd(&cnt[b * NC + tid], scnt[tid]);
}

// --------------------------------------------------- kernel 2: MLP heads ----
// One 64-thread block (1 wave) per (b,c) slot row. Weights staged to LDS with
// +1 pad (banks (lane+d)%32 -> 2-way = free); h[d] is a broadcast read.
__global__ __launch_bounds__(64) void mlp_kernel(
    const float* __restrict__ seg, const int* __restrict__ cnt,
    const float* wm1, const float* bm1, const float* wm2, const float* bm2,
    const float* wm3, const float* bm3,
    const float* wv1, const float* bv1, const float* wv2, const float* bv2,
    const float* wv3, const float* bv3,
    float* __restrict__ out)
{
    const int blk = blockIdx.x;               // b*NC + c
    const int lane = threadIdx.x;             // output dim

    __shared__ float h[DD];
    __shared__ float w_lds[DD * (DD + 1)];

    const float slot = seg[blk * DD + lane] / (float)cnt[blk];

    const float* Ws[2][3] = {{wm1, wm2, wm3}, {wv1, wv2, wv3}};
    const float* Bs[2][3] = {{bm1, bm2, bm3}, {bv1, bv2, bv3}};

    #pragma unroll
    for (int head = 0; head < 2; ++head) {
        __syncthreads();
        h[lane] = slot;
        float val = 0.f;
        #pragma unroll
        for (int layer = 0; layer < 3; ++layer) {
            const float* W = Ws[head][layer];
            const float bias = Bs[head][layer][lane];
            for (int i = 0; i < DD; ++i)      // coalesced 256B rows -> LDS
                w_lds[i * (DD + 1) + lane] = W[i * DD + lane];
            __syncthreads();
            float z = bias;
            #pragma unroll
            for (int d = 0; d < DD; ++d)      // y_j = sum_d h_d * W[j,d] + b_j
                z += h[d] * w_lds[lane * (DD + 1) + d];
            val = (layer < 2) ? fmaxf(z, 0.f)
                              : (2.f / (1.f + __expf(-z)) - 1.f);
            __syncthreads();
            h[lane] = val;
        }
        out[head * (BB * NC * DD) + blk * DD + lane] = val;
    }
}

// ------------------------------------- fallback: fused, zero-ws, 32 blocks --
__global__ __launch_bounds__(1024) void fused_fallback_kernel(
    const float* __restrict__ x, const int* __restrict__ labels,
    const float* wm1, const float* bm1, const float* wm2, const float* bm2,
    const float* wm3, const float* bm3,
    const float* wv1, const float* bv1, const float* wv2, const float* bv2,
    const float* wv3, const float* bv3,
    float* __restrict__ out)
{
    __shared__ float ssum[NC * DD];
    __shared__ int scnt[NC];
    __shared__ float hs[NC][DD];
    __shared__ float w_lds[DD * (DD + 1)];

    const int tid = threadIdx.x;
    const int b = blockIdx.x;
    const int wave = tid >> 6, lane = tid & 63;

    for (int i = tid; i < NC * DD; i += 1024) ssum[i] = 0.f;
    if (tid < NC) scnt[tid] = 0;
    __syncthreads();

    const int* lab = labels + b * SS;
    {   // ballot-based counts: wave w counts its 1024 rows, lane 0 commits
        int c_acc[NC];
        #pragma unroll
        for (int c = 0; c < NC; ++c) c_acc[c] = 0;
        for (int i = 0; i < 16; ++i) {
            int l = lab[wave * 1024 + i * 64 + lane];
            #pragma unroll
            for (int c = 0; c < NC; ++c)
                c_acc[c] += (int)__popcll(__ballot(l == c));
        }
        if (lane == 0) {
            #pragma unroll
            for (int c = 0; c < NC; ++c) atomicAdd(&scnt[c], c_acc[c]);
        }
    }

    const float* xb = x + ((long)b * SS + wave * 1024) * DD + lane;
    const int* labw = lab + wave * 1024;
    for (int r = 0; r < 1024; r += 8) {
        float v[8]; int l[8];
        #pragma unroll
        for (int u = 0; u < 8; ++u) {
            v[u] = xb[(r + u) * DD];
            l[u] = labw[r + u];
        }
        #pragma unroll
        for (int u = 0; u < 8; ++u)
            atomicAdd(&ssum[l[u] * DD + lane], v[u]);
    }
    __syncthreads();

    const int c = tid >> 6;                   // wave == cluster for active thr
    const bool act = (tid < NC * DD);
    float slot = 0.f;
    if (act) slot = ssum[c * DD + lane] / (float)scnt[c];

    const float* Ws[2][3] = {{wm1, wm2, wm3}, {wv1, wv2, wv3}};
    const float* Bs[2][3] = {{bm1, bm2, bm3}, {bv1, bv2, bv3}};

    #pragma unroll
    for (int head = 0; head < 2; ++head) {
        if (act) hs[c][lane] = slot;
        float val = 0.f;
        #pragma unroll
        for (int layer = 0; layer < 3; ++layer) {
            const float* W = Ws[head][layer];
            for (int i = tid; i < DD * DD; i += 1024)
                w_lds[(i >> 6) * (DD + 1) + (i & 63)] = W[i];
            __syncthreads();
            if (act) {
                float z = Bs[head][layer][lane];
                #pragma unroll
                for (int d = 0; d < DD; ++d)
                    z += hs[c][d] * w_lds[lane * (DD + 1) + d];
                val = (layer < 2) ? fmaxf(z, 0.f)
                                  : (2.f / (1.f + __expf(-z)) - 1.f);
            }
            __syncthreads();
            if (act) hs[c][lane] = val;
        }
        if (act)
            out[head * (BB * NC * DD) + (b * NC + c) * DD + lane] = val;
        __syncthreads();
    }
}

// ---------------------- kernel 3: init_mean / init_logvar from d_out (f32) --
__global__ __launch_bounds__(128) void init_kernel(
    const float* __restrict__ outro, const int* __restrict__ Kptr,
    float* __restrict__ out)
{
    const int t = threadIdx.x;                // 0..127
    const int head = t >> 6, lane = t & 63;
    const float* src = outro + head * (BB * NC * DD) + lane;
    float s = 0.f;
    for (int r = 0; r < BB * NC; ++r)         // 256B coalesced per r
        s += src[r * DD];
    out[2 * BB * NC * DD + t] = s / (float)(BB * Kptr[0]);
}

extern "C" void kernel_launch(void* const* d_in, const int* in_sizes, int n_in,
                              void* d_out, int out_size, void* d_ws, size_t ws_size,
                              hipStream_t stream)
{
    const float* x      = (const float*)d_in[0];
    const int*   labels = (const int*)d_in[1];
    const int*   K      = (const int*)d_in[2];
    const float* wm1 = (const float*)d_in[3];
    const float* bm1 = (const float*)d_in[4];
    const float* wm2 = (const float*)d_in[5];
    const float* bm2 = (const float*)d_in[6];
    const float* wm3 = (const float*)d_in[7];
    const float* bm3 = (const float*)d_in[8];
    const float* wv1 = (const float*)d_in[9];
    const float* bv1 = (const float*)d_in[10];
    const float* wv2 = (const float*)d_in[11];
    const float* bv2 = (const float*)d_in[12];
    const float* wv3 = (const float*)d_in[13];
    const float* bv3 = (const float*)d_in[14];
    float* out = (float*)d_out;

    if (ws_size >= (size_t)WS_WORDS * 4) {
        float* seg = (float*)d_ws;
        int*   cnt = (int*)((char*)d_ws + (size_t)BB * NC * DD * 4);
        zero_ws_kernel<<<(WS_WORDS + 255) / 256, 256, 0, stream>>>((int*)d_ws, WS_WORDS);
        seg_kernel<<<BB * SCHUNKS, 256, 0, stream>>>(x, labels, seg, cnt);
        mlp_kernel<<<BB * NC, 64, 0, stream>>>(
            seg, cnt,
            wm1, bm1, wm2, bm2, wm3, bm3,
            wv1, bv1, wv2, bv2, wv3, bv3, out);
    } else {
        fused_fallback_kernel<<<BB, 1024, 0, stream>>>(
            x, labels,
            wm1, bm1, wm2, bm2, wm3, bm3,
            wv1, bv1, wv2, bv2, wv3, bv3, out);
    }
    init_kernel<<<1, 128, 0, stream>>>((const float*)d_out, K, out);
}